// Round 4
// baseline (486.692 us; speedup 1.0000x reference)
//
#include <hip/hip_runtime.h>
#include <math.h>
#include <limits.h>

// Match numpy op-for-op: no fma contraction anywhere.
#pragma clang fp contract(off)

#define TPB 256
#define KTOP 10
#define MAXG 512

typedef unsigned int u32;
typedef unsigned char u8;

// pairwise IoU, identical op order to the numpy reference
__device__ __forceinline__ float f_iou(float ax0, float ay0, float ax1, float ay1,
                                       float bx0, float by0, float bx1, float by1) {
  float tlx = fmaxf(ax0, bx0);
  float tly = fmaxf(ay0, by0);
  float brx = fminf(ax1, bx1);
  float bry = fminf(ay1, by1);
  float w = fmaxf(brx - tlx, 0.0f);
  float h = fmaxf(bry - tly, 0.0f);
  float inter = w * h;
  float aa = fmaxf(ax1 - ax0, 0.0f) * fmaxf(ay1 - ay0, 0.0f);
  float ab = fmaxf(bx1 - bx0, 0.0f) * fmaxf(by1 - by0, 0.0f);
  float uni = aa + ab - inter;
  return inter / fmaxf(uni, 1e-7f);
}

// cost(n,g), identical op order to reference. iou_masked = valid ? iou : 0.
__device__ __forceinline__ float f_cost(float iou_masked, float p, float sumL1v,
                                        float px, float py, float sx, float sy,
                                        float bx0, float by0, float bx1, float by1,
                                        int vld) {
  if (!vld) return 100000000.0f;  // BIG
  float L  = fmaxf(logf(p), -100.0f);
  float L1 = fmaxf(log1pf(-p), -100.0f);
  float cls = -(L - L1) - sumL1v;
  float l_ = px - bx0, t_ = py - by0, r_ = bx1 - px, b_ = by1 - py;
  bool ing = fminf(fminf(l_, t_), fminf(r_, b_)) > 0.0f;
  float gcx = (bx0 + bx1) * 0.5f;
  float gcy = (by0 + by1) * 0.5f;
  float cl = px - (gcx - 2.5f * sx);
  float ct = py - (gcy - 2.5f * sy);
  float cr = (gcx + 2.5f * sx) - px;
  float cb = (gcy + 2.5f * sy) - py;
  bool inc = fminf(fminf(cl, ct), fminf(cr, cb)) > 0.0f;
  float icost = -logf(iou_masked + 1e-7f);
  return (cls * 1.0f + icost * 3.0f) + ((ing && inc) ? 0.0f : 100000.0f);
}

// Fallback: distinct sentinel so a too-small workspace is diagnosable.
__global__ __launch_bounds__(TPB) void k_fallback(float* out, int Nout) {
  int n = blockIdx.x * blockDim.x + threadIdx.x;
  if (n >= Nout) return;
  out[n] = 0.0f;
  out[Nout + n] = -1.0f;
  out[2 * Nout + n] = -70000.0f;
}

// Kernel 1: per-anchor valid flag + sum(L1) (numpy pairwise order) + zero packed
__global__ __launch_bounds__(TPB) void k_pre(
    const float* pred, const float* priors, const float* gtb,
    float* sumL1, u8* validArr, u32* packed,
    int N, int G, int C)
{
  __shared__ float sg[MAXG * 4];
  for (int i = threadIdx.x; i < G * 4; i += blockDim.x) sg[i] = gtb[i];
  __syncthreads();
  int n = blockIdx.x * blockDim.x + threadIdx.x;
  if (n >= N) return;
  float px = priors[n * 4 + 0];
  float py = priors[n * 4 + 1];
  float sx = priors[n * 4 + 2];
  float sy = priors[n * 4 + 3];
  bool valid = false;
  for (int g = 0; g < G; ++g) {
    float x0 = sg[g * 4 + 0], y0 = sg[g * 4 + 1], x1 = sg[g * 4 + 2], y1 = sg[g * 4 + 3];
    float l_ = px - x0, t_ = py - y0, r_ = x1 - px, b_ = y1 - py;
    bool ing = fminf(fminf(l_, t_), fminf(r_, b_)) > 0.0f;
    float gcx = (x0 + x1) * 0.5f, gcy = (y0 + y1) * 0.5f;
    float cl = px - (gcx - 2.5f * sx), ct = py - (gcy - 2.5f * sy);
    float cr = (gcx + 2.5f * sx) - px, cb = (gcy + 2.5f * sy) - py;
    bool inc = fminf(fminf(cl, ct), fminf(cr, cb)) > 0.0f;
    valid = valid || ing || inc;
  }
  validArr[n] = valid ? 1 : 0;

  // sum over C of clip(log1p(-p), -100), numpy pairwise-sum order (8 accs;
  // C=80 = 8 + 9 full blocks of 8, no tail).
  const float* pr = pred + (size_t)n * C;
  float s;
  if (C >= 8) {
    float r0 = fmaxf(log1pf(-pr[0]), -100.0f);
    float r1 = fmaxf(log1pf(-pr[1]), -100.0f);
    float r2 = fmaxf(log1pf(-pr[2]), -100.0f);
    float r3 = fmaxf(log1pf(-pr[3]), -100.0f);
    float r4 = fmaxf(log1pf(-pr[4]), -100.0f);
    float r5 = fmaxf(log1pf(-pr[5]), -100.0f);
    float r6 = fmaxf(log1pf(-pr[6]), -100.0f);
    float r7 = fmaxf(log1pf(-pr[7]), -100.0f);
    int i = 8;
    int lim = C - (C % 8);
    for (; i < lim; i += 8) {
      r0 += fmaxf(log1pf(-pr[i + 0]), -100.0f);
      r1 += fmaxf(log1pf(-pr[i + 1]), -100.0f);
      r2 += fmaxf(log1pf(-pr[i + 2]), -100.0f);
      r3 += fmaxf(log1pf(-pr[i + 3]), -100.0f);
      r4 += fmaxf(log1pf(-pr[i + 4]), -100.0f);
      r5 += fmaxf(log1pf(-pr[i + 5]), -100.0f);
      r6 += fmaxf(log1pf(-pr[i + 6]), -100.0f);
      r7 += fmaxf(log1pf(-pr[i + 7]), -100.0f);
    }
    s = ((r0 + r1) + (r2 + r3)) + ((r4 + r5) + (r6 + r7));
    for (; i < C; ++i) s += fmaxf(log1pf(-pr[i]), -100.0f);
  } else {
    s = 0.0f;
    for (int i = 0; i < C; ++i) s += fmaxf(log1pf(-pr[i]), -100.0f);
  }
  sumL1[n] = s;
  packed[n] = 0;  // ws is re-poisoned every launch — must re-zero
}

// Kernel 2: one block per GT. Per-thread stable top-10 lists, then 10 rounds
// of block tournament (parallel tree reduce, (value,index) tie-break), winner
// pops its head. Scatter first dynamic_k candidates into packed counters.
__global__ __launch_bounds__(TPB) void k_assign(
    const float* pred, const float* priors, const float* dec, const float* gtb,
    const int* gtl, const float* sumL1, const u8* validArr, u32* packed,
    int N, int C)
{
  int g = blockIdx.x;
  int tid = threadIdx.x;
  float bx0 = gtb[g * 4 + 0];
  float by0 = gtb[g * 4 + 1];
  float bx1 = gtb[g * 4 + 2];
  float by1 = gtb[g * 4 + 3];
  int lab = gtl[g];
  if (lab < 0) lab = 0;
  if (lab >= C) lab = C - 1;

  float iv[KTOP]; int ii[KTOP];
  float cv[KTOP]; int ci[KTOP];
  for (int j = 0; j < KTOP; ++j) { iv[j] = -1e30f; ii[j] = INT_MAX; cv[j] = 1e30f; ci[j] = INT_MAX; }

  for (int n = tid; n < N; n += TPB) {
    float ax0 = dec[n * 4 + 0];
    float ay0 = dec[n * 4 + 1];
    float ax1 = dec[n * 4 + 2];
    float ay1 = dec[n * 4 + 3];
    int vld = validArr[n];
    float iou = f_iou(ax0, ay0, ax1, ay1, bx0, by0, bx1, by1);
    if (!vld) iou = 0.0f;
    // stable descending insert: strict '>' keeps earlier (smaller-n) ties first
    if (iou > iv[KTOP - 1]) {
      int j = KTOP - 1;
      while (j > 0 && iou > iv[j - 1]) { iv[j] = iv[j - 1]; ii[j] = ii[j - 1]; --j; }
      iv[j] = iou; ii[j] = n;
    }
    float p = pred[(size_t)n * C + lab];
    float px = priors[n * 4 + 0];
    float py = priors[n * 4 + 1];
    float sx = priors[n * 4 + 2];
    float sy = priors[n * 4 + 3];
    float c = f_cost(iou, p, sumL1[n], px, py, sx, sy, bx0, by0, bx1, by1, vld);
    if (c < cv[KTOP - 1]) {
      int j = KTOP - 1;
      while (j > 0 && c < cv[j - 1]) { cv[j] = cv[j - 1]; ci[j] = ci[j - 1]; --j; }
      cv[j] = c; ci[j] = n;
    }
  }

  __shared__ float sv[TPB];
  __shared__ int   si[TPB];
  __shared__ float rv[KTOP];
  __shared__ int   ri[KTOP];

  // --- phase 1: block top-10 IoU values (for dynamic_k) ---
  for (int r = 0; r < KTOP; ++r) {
    sv[tid] = iv[0]; si[tid] = ii[0];
    __syncthreads();
    for (int s = TPB / 2; s > 0; s >>= 1) {
      if (tid < s) {
        float v2 = sv[tid + s]; int i2 = si[tid + s];
        float v1 = sv[tid];     int i1 = si[tid];
        if (v2 > v1 || (v2 == v1 && i2 < i1)) { sv[tid] = v2; si[tid] = i2; }
      }
      __syncthreads();
    }
    if (tid == 0) rv[r] = sv[0];
    int win = si[0];
    __syncthreads();   // everyone read si[0] before next round overwrites
    if (ii[0] == win) {  // winner pops its head (anchor indices are unique)
      for (int j = 0; j < KTOP - 1; ++j) { iv[j] = iv[j + 1]; ii[j] = ii[j + 1]; }
      iv[KTOP - 1] = -1e30f; ii[KTOP - 1] = INT_MAX;
    }
  }

  int dk_local = 1;
  if (tid == 0) {
    // numpy pairwise order for a 10-element sum: tree of first 8, then +a8 +a9
    float s8 = ((rv[0] + rv[1]) + (rv[2] + rv[3])) + ((rv[4] + rv[5]) + (rv[6] + rv[7]));
    s8 += rv[8];
    s8 += rv[9];
    int dk = (int)s8;  // trunc toward zero == astype(int32)
    if (dk < 1) dk = 1;
    if (dk > KTOP) dk = KTOP;
    dk_local = dk;
  }

  // --- phase 2: block top-10 lowest cost (indices) ---
  for (int r = 0; r < KTOP; ++r) {
    sv[tid] = cv[0]; si[tid] = ci[0];
    __syncthreads();
    for (int s = TPB / 2; s > 0; s >>= 1) {
      if (tid < s) {
        float v2 = sv[tid + s]; int i2 = si[tid + s];
        float v1 = sv[tid];     int i1 = si[tid];
        if (v2 < v1 || (v2 == v1 && i2 < i1)) { sv[tid] = v2; si[tid] = i2; }
      }
      __syncthreads();
    }
    if (tid == 0) ri[r] = si[0];
    int win = si[0];
    __syncthreads();
    if (ci[0] == win) {
      for (int j = 0; j < KTOP - 1; ++j) { cv[j] = cv[j + 1]; ci[j] = ci[j + 1]; }
      cv[KTOP - 1] = 1e30f; ci[KTOP - 1] = INT_MAX;
    }
  }

  if (tid == 0) {
    for (int k = 0; k < dk_local; ++k) {
      int n = ri[k];
      if (n >= 0 && n < N) {
        // count in high 16 bits; sum of g in low 16 (exact g when count==1).
        // count<=G<=128, sum(g)<=128*127=16256 — no field overflow.
        atomicAdd(&packed[n], (1u << 16) | (u32)g);
      }
    }
  }
}

// Kernel 3: per-anchor resolution + f32 outputs (sole writer of d_out)
__global__ __launch_bounds__(TPB) void k_final(
    const float* pred, const float* priors, const float* dec, const float* gtb,
    const int* gtl, const float* sumL1, const u8* validArr, const u32* packed,
    float* out, int N, int G, int C, int Nout)
{
  __shared__ float sg[MAXG * 4];
  __shared__ int sl[MAXG];
  for (int i = threadIdx.x; i < G * 4; i += blockDim.x) sg[i] = gtb[i];
  for (int i = threadIdx.x; i < G; i += blockDim.x) {
    int lb = gtl[i];
    if (lb < 0) lb = 0;
    if (lb >= C) lb = C - 1;
    sl[i] = lb;
  }
  __syncthreads();
  int n = blockIdx.x * blockDim.x + threadIdx.x;
  if (n >= N || n >= Nout) return;
  u32 pk = packed[n];
  int cnt = (int)(pk >> 16);
  float o0 = 0.0f, o1 = -1.0f, o2 = -100000.0f;
  if (cnt > 0) {
    int vld = validArr[n];
    float ax0 = dec[n * 4 + 0];
    float ay0 = dec[n * 4 + 1];
    float ax1 = dec[n * 4 + 2];
    float ay1 = dec[n * 4 + 3];
    int g;
    if (cnt == 1) {
      g = (int)(pk & 0xFFFFu);
    } else {
      // multi-match: argmin over full cost row (first-min wins, like np.argmin)
      float px = priors[n * 4 + 0];
      float py = priors[n * 4 + 1];
      float sx = priors[n * 4 + 2];
      float sy = priors[n * 4 + 3];
      float s1 = sumL1[n];
      float best = 1e30f; int bg = 0;
      for (int gg = 0; gg < G; ++gg) {
        float x0 = sg[gg * 4 + 0], y0 = sg[gg * 4 + 1], x1 = sg[gg * 4 + 2], y1 = sg[gg * 4 + 3];
        float iou = f_iou(ax0, ay0, ax1, ay1, x0, y0, x1, y1);
        if (!vld) iou = 0.0f;
        float p = pred[(size_t)n * C + sl[gg]];
        float c = f_cost(iou, p, s1, px, py, sx, sy, x0, y0, x1, y1, vld);
        if (c < best) { best = c; bg = gg; }
      }
      g = bg;
    }
    if (g < 0) g = 0;
    if (g >= G) g = G - 1;
    float x0 = sg[g * 4 + 0], y0 = sg[g * 4 + 1], x1 = sg[g * 4 + 2], y1 = sg[g * 4 + 3];
    float iou = f_iou(ax0, ay0, ax1, ay1, x0, y0, x1, y1);
    if (!vld) iou = 0.0f;
    o0 = (float)g; o1 = 1.0f; o2 = iou;
  }
  out[n]            = o0;
  out[Nout + n]     = o1;
  out[2 * Nout + n] = o2;
}

extern "C" void kernel_launch(void* const* d_in, const int* in_sizes, int n_in,
                              void* d_out, int out_size, void* d_ws, size_t ws_size,
                              hipStream_t stream) {
  const float* pred   = (const float*)d_in[0];  // (N,C) f32
  const float* priors = (const float*)d_in[1];  // (N,4) f32
  const float* dec    = (const float*)d_in[2];  // (N,4) f32
  const float* gtb    = (const float*)d_in[3];  // (G,4) f32
  const int*   gtl    = (const int*)d_in[4];    // (G,)  int32
  int N = in_sizes[2] / 4;
  int G = in_sizes[3] / 4;
  if (G > MAXG) G = MAXG;
  int C = in_sizes[0] / N;
  int Nout = out_size / 3;
  float* out = (float*)d_out;

  // workspace: packed u32 (4N) | sumL1 f32 (4N) | valid u8 (N)  = 9N bytes
  size_t need = (size_t)N * 9;
  dim3 b(TPB);
  int nblk = (N + TPB - 1) / TPB;
  int oblk = (Nout + TPB - 1) / TPB;
  if (ws_size < need || d_ws == nullptr) {
    k_fallback<<<oblk, b, 0, stream>>>(out, Nout);  // sentinel: -70000 at out2
    return;
  }
  u32* packed  = (u32*)d_ws;
  float* sumL1 = (float*)((char*)d_ws + (size_t)N * 4);
  u8* validArr = (u8*)((char*)d_ws + (size_t)N * 8);

  k_pre<<<nblk, b, 0, stream>>>(pred, priors, gtb, sumL1, validArr, packed, N, G, C);
  k_assign<<<G, b, 0, stream>>>(pred, priors, dec, gtb, gtl, sumL1, validArr, packed, N, C);
  k_final<<<nblk, b, 0, stream>>>(pred, priors, dec, gtb, gtl, sumL1, validArr, packed, out, N, G, C, Nout);
}

// Round 5
// 312.718 us; speedup vs baseline: 1.5563x; 1.5563x over previous
//
#include <hip/hip_runtime.h>
#include <math.h>
#include <limits.h>

// Match numpy op-for-op: no fma contraction anywhere.
#pragma clang fp contract(off)

#define TPB 256
#define KTOP 10
#define NSPLIT 8
#define MAXG 512

typedef unsigned int u32;
typedef unsigned char u8;

// pairwise IoU, identical op order to the numpy reference
__device__ __forceinline__ float f_iou(float ax0, float ay0, float ax1, float ay1,
                                       float bx0, float by0, float bx1, float by1) {
  float tlx = fmaxf(ax0, bx0);
  float tly = fmaxf(ay0, by0);
  float brx = fminf(ax1, bx1);
  float bry = fminf(ay1, by1);
  float w = fmaxf(brx - tlx, 0.0f);
  float h = fmaxf(bry - tly, 0.0f);
  float inter = w * h;
  float aa = fmaxf(ax1 - ax0, 0.0f) * fmaxf(ay1 - ay0, 0.0f);
  float ab = fmaxf(bx1 - bx0, 0.0f) * fmaxf(by1 - by0, 0.0f);
  float uni = aa + ab - inter;
  return inter / fmaxf(uni, 1e-7f);
}

// cost(n,g), identical op order to reference. iou_masked = valid ? iou : 0.
__device__ __forceinline__ float f_cost(float iou_masked, float p, float sumL1v,
                                        float px, float py, float sx, float sy,
                                        float bx0, float by0, float bx1, float by1,
                                        int vld) {
  if (!vld) return 100000000.0f;  // BIG
  float L  = fmaxf(logf(p), -100.0f);
  float L1 = fmaxf(log1pf(-p), -100.0f);
  float cls = -(L - L1) - sumL1v;
  float l_ = px - bx0, t_ = py - by0, r_ = bx1 - px, b_ = by1 - py;
  bool ing = fminf(fminf(l_, t_), fminf(r_, b_)) > 0.0f;
  float gcx = (bx0 + bx1) * 0.5f;
  float gcy = (by0 + by1) * 0.5f;
  float cl = px - (gcx - 2.5f * sx);
  float ct = py - (gcy - 2.5f * sy);
  float cr = (gcx + 2.5f * sx) - px;
  float cb = (gcy + 2.5f * sy) - py;
  bool inc = fminf(fminf(cl, ct), fminf(cr, cb)) > 0.0f;
  float icost = -logf(iou_masked + 1e-7f);
  return (cls * 1.0f + icost * 3.0f) + ((ing && inc) ? 0.0f : 100000.0f);
}

// Fallback: distinct sentinel so a too-small workspace is diagnosable.
__global__ __launch_bounds__(TPB) void k_fallback(float* out, int Nout) {
  int n = blockIdx.x * blockDim.x + threadIdx.x;
  if (n >= Nout) return;
  out[n] = 0.0f;
  out[Nout + n] = -1.0f;
  out[2 * Nout + n] = -70000.0f;
}

// Kernel 1: 8 threads per anchor. valid flag via shfl-OR over g-strides;
// sum(L1) via 8 lane-accumulators + shfl-down tree == numpy pairwise order.
__global__ __launch_bounds__(TPB) void k_pre(
    const float* pred, const float* priors, const float* gtb,
    float* sumL1, u8* validArr, u32* packed,
    int N, int G, int C)
{
  __shared__ float sg[MAXG * 4];
  for (int i = threadIdx.x; i < G * 4; i += blockDim.x) sg[i] = gtb[i];
  __syncthreads();
  int t = blockIdx.x * blockDim.x + threadIdx.x;
  int n = t >> 3;
  int j = t & 7;
  if (n >= N) return;
  const float4 pv = reinterpret_cast<const float4*>(priors)[n];
  float px = pv.x, py = pv.y, sx = pv.z, sy = pv.w;

  int valid = 0;
  for (int g = j; g < G; g += 8) {
    float x0 = sg[g * 4 + 0], y0 = sg[g * 4 + 1], x1 = sg[g * 4 + 2], y1 = sg[g * 4 + 3];
    float l_ = px - x0, t_ = py - y0, r_ = x1 - px, b_ = y1 - py;
    bool ing = fminf(fminf(l_, t_), fminf(r_, b_)) > 0.0f;
    float gcx = (x0 + x1) * 0.5f, gcy = (y0 + y1) * 0.5f;
    float cl = px - (gcx - 2.5f * sx), ct = py - (gcy - 2.5f * sy);
    float cr = (gcx + 2.5f * sx) - px, cb = (gcy + 2.5f * sy) - py;
    bool inc = fminf(fminf(cl, ct), fminf(cr, cb)) > 0.0f;
    valid |= (ing || inc) ? 1 : 0;
  }
  valid |= __shfl_xor(valid, 1, 8);
  valid |= __shfl_xor(valid, 2, 8);
  valid |= __shfl_xor(valid, 4, 8);

  // lane j accumulates terms i ≡ j (mod 8), ascending — identical to numpy's
  // 8-accumulator pairwise loop; shfl-down tree matches ((r0+r1)+(r2+r3))+(...)
  const float* pr = pred + (size_t)n * C;
  int lim = C - (C % 8);
  float r = 0.0f;
  for (int i = j; i < lim; i += 8) r += fmaxf(log1pf(-pr[i]), -100.0f);
  r += __shfl_down(r, 1, 8);
  r += __shfl_down(r, 2, 8);
  r += __shfl_down(r, 4, 8);
  if (j == 0) {
    for (int i = lim; i < C; ++i) r += fmaxf(log1pf(-pr[i]), -100.0f);
    sumL1[n] = r;
    validArr[n] = (u8)valid;
    packed[n] = 0;  // ws is re-poisoned every launch — must re-zero
  }
}

// Kernel 2a: one block per (g, chunk). Per-thread stable top-10 over the
// chunk, block tournament (tie -> smaller index), write sorted partial
// top-10 (iou and cost, values+indices) to workspace.
__global__ __launch_bounds__(TPB) void k_assign_part(
    const float* pred, const float* priors, const float* dec, const float* gtb,
    const int* gtl, const float* sumL1, const u8* validArr,
    float* iouV, int* iouI, float* costV, int* costI,
    int N, int G, int C)
{
  int bid = blockIdx.x;
  int g = bid / NSPLIT;
  int s = bid % NSPLIT;
  int chunk = (N + NSPLIT - 1) / NSPLIT;
  int start = s * chunk;
  int end = start + chunk; if (end > N) end = N;
  int tid = threadIdx.x;
  float bx0 = gtb[g * 4 + 0];
  float by0 = gtb[g * 4 + 1];
  float bx1 = gtb[g * 4 + 2];
  float by1 = gtb[g * 4 + 3];
  int lab = gtl[g];
  if (lab < 0) lab = 0;
  if (lab >= C) lab = C - 1;

  float iv[KTOP]; int ii[KTOP];
  float cv[KTOP]; int ci[KTOP];
  for (int j = 0; j < KTOP; ++j) { iv[j] = -1e30f; ii[j] = INT_MAX; cv[j] = 1e30f; ci[j] = INT_MAX; }

  const float4* dec4 = reinterpret_cast<const float4*>(dec);
  const float4* pri4 = reinterpret_cast<const float4*>(priors);

  for (int n = start + tid; n < end; n += TPB) {
    float4 dv = dec4[n];
    int vld = validArr[n];
    float iou = f_iou(dv.x, dv.y, dv.z, dv.w, bx0, by0, bx1, by1);
    if (!vld) iou = 0.0f;
    // stable descending insert: strict '>' keeps earlier (smaller-n) ties first
    if (iou > iv[KTOP - 1]) {
      int j = KTOP - 1;
      while (j > 0 && iou > iv[j - 1]) { iv[j] = iv[j - 1]; ii[j] = ii[j - 1]; --j; }
      iv[j] = iou; ii[j] = n;
    }
    float p = pred[(size_t)n * C + lab];
    float4 pv = pri4[n];
    float c = f_cost(iou, p, sumL1[n], pv.x, pv.y, pv.z, pv.w, bx0, by0, bx1, by1, vld);
    if (c < cv[KTOP - 1]) {
      int j = KTOP - 1;
      while (j > 0 && c < cv[j - 1]) { cv[j] = cv[j - 1]; ci[j] = ci[j - 1]; --j; }
      cv[j] = c; ci[j] = n;
    }
  }

  __shared__ float sv[TPB];
  __shared__ int   si[TPB];
  int base = bid * KTOP;

  // --- phase 1: block top-10 IoU (values+indices) ---
  for (int r = 0; r < KTOP; ++r) {
    sv[tid] = iv[0]; si[tid] = ii[0];
    __syncthreads();
    for (int st = TPB / 2; st > 0; st >>= 1) {
      if (tid < st) {
        float v2 = sv[tid + st]; int i2 = si[tid + st];
        float v1 = sv[tid];      int i1 = si[tid];
        if (v2 > v1 || (v2 == v1 && i2 < i1)) { sv[tid] = v2; si[tid] = i2; }
      }
      __syncthreads();
    }
    if (tid == 0) { iouV[base + r] = sv[0]; iouI[base + r] = si[0]; }
    int win = si[0];
    __syncthreads();   // all read si[0] before next round overwrites
    if (ii[0] == win) {  // winner pops its head (anchor indices unique)
      for (int j = 0; j < KTOP - 1; ++j) { iv[j] = iv[j + 1]; ii[j] = ii[j + 1]; }
      iv[KTOP - 1] = -1e30f; ii[KTOP - 1] = INT_MAX;
    }
  }

  // --- phase 2: block top-10 lowest cost (values+indices) ---
  for (int r = 0; r < KTOP; ++r) {
    sv[tid] = cv[0]; si[tid] = ci[0];
    __syncthreads();
    for (int st = TPB / 2; st > 0; st >>= 1) {
      if (tid < st) {
        float v2 = sv[tid + st]; int i2 = si[tid + st];
        float v1 = sv[tid];      int i1 = si[tid];
        if (v2 < v1 || (v2 == v1 && i2 < i1)) { sv[tid] = v2; si[tid] = i2; }
      }
      __syncthreads();
    }
    if (tid == 0) { costV[base + r] = sv[0]; costI[base + r] = si[0]; }
    int win = si[0];
    __syncthreads();
    if (ci[0] == win) {
      for (int j = 0; j < KTOP - 1; ++j) { cv[j] = cv[j + 1]; ci[j] = ci[j + 1]; }
      cv[KTOP - 1] = 1e30f; ci[KTOP - 1] = INT_MAX;
    }
  }
}

// Kernel 2b: one thread per g. 8-way sorted merge of partial lists
// ((value,index) tie-break == global stable top-k), dynamic_k, scatter.
__global__ __launch_bounds__(64) void k_merge(
    const float* iouV, const int* iouI, const float* costV, const int* costI,
    u32* packed, int G, int N)
{
  int g = blockIdx.x * blockDim.x + threadIdx.x;
  if (g >= G) return;
  int base = g * NSPLIT * KTOP;

  // --- merge iou (descending), collect 10 values in sorted order ---
  int hp[NSPLIT]; float hv[NSPLIT]; int hi[NSPLIT];
  for (int s = 0; s < NSPLIT; ++s) {
    hp[s] = 0; hv[s] = iouV[base + s * KTOP]; hi[s] = iouI[base + s * KTOP];
  }
  float rv[KTOP];
  for (int r = 0; r < KTOP; ++r) {
    int bs = 0;
    for (int s = 1; s < NSPLIT; ++s)
      if (hv[s] > hv[bs] || (hv[s] == hv[bs] && hi[s] < hi[bs])) bs = s;
    rv[r] = hv[bs];
    int p = ++hp[bs];
    if (p < KTOP) { hv[bs] = iouV[base + bs * KTOP + p]; hi[bs] = iouI[base + bs * KTOP + p]; }
    else          { hv[bs] = -1e30f; hi[bs] = INT_MAX; }
  }
  // numpy pairwise order for a 10-element sum: tree of first 8, then +a8 +a9
  float s8 = ((rv[0] + rv[1]) + (rv[2] + rv[3])) + ((rv[4] + rv[5]) + (rv[6] + rv[7]));
  s8 += rv[8];
  s8 += rv[9];
  int dk = (int)s8;  // trunc toward zero == astype(int32)
  if (dk < 1) dk = 1;
  if (dk > KTOP) dk = KTOP;

  // --- merge cost (ascending), scatter first dk indices ---
  for (int s = 0; s < NSPLIT; ++s) {
    hp[s] = 0; hv[s] = costV[base + s * KTOP]; hi[s] = costI[base + s * KTOP];
  }
  for (int r = 0; r < dk; ++r) {
    int bs = 0;
    for (int s = 1; s < NSPLIT; ++s)
      if (hv[s] < hv[bs] || (hv[s] == hv[bs] && hi[s] < hi[bs])) bs = s;
    int n = hi[bs];
    if (n >= 0 && n < N) {
      // count in high 16 bits; sum of g in low 16 (exact g when count==1).
      atomicAdd(&packed[n], (1u << 16) | (u32)g);
    }
    int p = ++hp[bs];
    if (p < KTOP) { hv[bs] = costV[base + bs * KTOP + p]; hi[bs] = costI[base + bs * KTOP + p]; }
    else          { hv[bs] = 1e30f; hi[bs] = INT_MAX; }
  }
}

// Kernel 3: per-anchor resolution + f32 outputs (sole writer of d_out)
__global__ __launch_bounds__(TPB) void k_final(
    const float* pred, const float* priors, const float* dec, const float* gtb,
    const int* gtl, const float* sumL1, const u8* validArr, const u32* packed,
    float* out, int N, int G, int C, int Nout)
{
  __shared__ float sg[MAXG * 4];
  __shared__ int sl[MAXG];
  for (int i = threadIdx.x; i < G * 4; i += blockDim.x) sg[i] = gtb[i];
  for (int i = threadIdx.x; i < G; i += blockDim.x) {
    int lb = gtl[i];
    if (lb < 0) lb = 0;
    if (lb >= C) lb = C - 1;
    sl[i] = lb;
  }
  __syncthreads();
  int n = blockIdx.x * blockDim.x + threadIdx.x;
  if (n >= N || n >= Nout) return;
  u32 pk = packed[n];
  int cnt = (int)(pk >> 16);
  float o0 = 0.0f, o1 = -1.0f, o2 = -100000.0f;
  if (cnt > 0) {
    int vld = validArr[n];
    const float4 dv = reinterpret_cast<const float4*>(dec)[n];
    float ax0 = dv.x, ay0 = dv.y, ax1 = dv.z, ay1 = dv.w;
    int g;
    if (cnt == 1) {
      g = (int)(pk & 0xFFFFu);
    } else {
      // multi-match: argmin over full cost row (first-min wins, like np.argmin)
      const float4 pv = reinterpret_cast<const float4*>(priors)[n];
      float px = pv.x, py = pv.y, sx = pv.z, sy = pv.w;
      float s1 = sumL1[n];
      float best = 1e30f; int bg = 0;
      for (int gg = 0; gg < G; ++gg) {
        float x0 = sg[gg * 4 + 0], y0 = sg[gg * 4 + 1], x1 = sg[gg * 4 + 2], y1 = sg[gg * 4 + 3];
        float iou = f_iou(ax0, ay0, ax1, ay1, x0, y0, x1, y1);
        if (!vld) iou = 0.0f;
        float p = pred[(size_t)n * C + sl[gg]];
        float c = f_cost(iou, p, s1, px, py, sx, sy, x0, y0, x1, y1, vld);
        if (c < best) { best = c; bg = gg; }
      }
      g = bg;
    }
    if (g < 0) g = 0;
    if (g >= G) g = G - 1;
    float x0 = sg[g * 4 + 0], y0 = sg[g * 4 + 1], x1 = sg[g * 4 + 2], y1 = sg[g * 4 + 3];
    float iou = f_iou(ax0, ay0, ax1, ay1, x0, y0, x1, y1);
    if (!vld) iou = 0.0f;
    o0 = (float)g; o1 = 1.0f; o2 = iou;
  }
  out[n]            = o0;
  out[Nout + n]     = o1;
  out[2 * Nout + n] = o2;
}

extern "C" void kernel_launch(void* const* d_in, const int* in_sizes, int n_in,
                              void* d_out, int out_size, void* d_ws, size_t ws_size,
                              hipStream_t stream) {
  const float* pred   = (const float*)d_in[0];  // (N,C) f32
  const float* priors = (const float*)d_in[1];  // (N,4) f32
  const float* dec    = (const float*)d_in[2];  // (N,4) f32
  const float* gtb    = (const float*)d_in[3];  // (G,4) f32
  const int*   gtl    = (const int*)d_in[4];    // (G,)  int32
  int N = in_sizes[2] / 4;
  int G = in_sizes[3] / 4;
  if (G > MAXG) G = MAXG;
  int C = in_sizes[0] / N;
  int Nout = out_size / 3;
  float* out = (float*)d_out;

  // ws: packed u32[N] | sumL1 f32[N] | valid u8[N] (pad16) |
  //     iouV f32[G*S*10] | iouI i32 | costV f32 | costI i32
  size_t off0 = 0;
  size_t off1 = off0 + (size_t)N * 4;
  size_t off2 = off1 + (size_t)N * 4;
  size_t offP = (off2 + (size_t)N + 15) & ~(size_t)15;
  size_t plist = (size_t)G * NSPLIT * KTOP * 4;
  size_t need = offP + plist * 4;

  dim3 b(TPB);
  int nblk = (N + TPB - 1) / TPB;
  int oblk = (Nout + TPB - 1) / TPB;
  if (ws_size < need || d_ws == nullptr) {
    k_fallback<<<oblk, b, 0, stream>>>(out, Nout);  // sentinel: -70000 at out2
    return;
  }
  char* wsb = (char*)d_ws;
  u32* packed   = (u32*)(wsb + off0);
  float* sumL1  = (float*)(wsb + off1);
  u8* validArr  = (u8*)(wsb + off2);
  float* iouV   = (float*)(wsb + offP);
  int*   iouI   = (int*)(wsb + offP + plist);
  float* costV  = (float*)(wsb + offP + plist * 2);
  int*   costI  = (int*)(wsb + offP + plist * 3);

  int preblk = ((N * 8) + TPB - 1) / TPB;
  k_pre<<<preblk, b, 0, stream>>>(pred, priors, gtb, sumL1, validArr, packed, N, G, C);
  k_assign_part<<<G * NSPLIT, b, 0, stream>>>(pred, priors, dec, gtb, gtl, sumL1, validArr,
                                              iouV, iouI, costV, costI, N, G, C);
  k_merge<<<(G + 63) / 64, dim3(64), 0, stream>>>(iouV, iouI, costV, costI, packed, G, N);
  k_final<<<nblk, b, 0, stream>>>(pred, priors, dec, gtb, gtl, sumL1, validArr, packed, out, N, G, C, Nout);
}

// Round 6
// 186.111 us; speedup vs baseline: 2.6151x; 1.6803x over previous
//
#include <hip/hip_runtime.h>
#include <math.h>
#include <limits.h>

// Match numpy op-for-op: no fma contraction anywhere.
#pragma clang fp contract(off)

#define TPB 256
#define KTOP 10
#define NSPLIT 8
#define MAXG 512
#define MAXMULTI 4096

typedef unsigned int u32;
typedef unsigned char u8;

// pairwise IoU, identical op order to the numpy reference
__device__ __forceinline__ float f_iou(float ax0, float ay0, float ax1, float ay1,
                                       float bx0, float by0, float bx1, float by1) {
  float tlx = fmaxf(ax0, bx0);
  float tly = fmaxf(ay0, by0);
  float brx = fminf(ax1, bx1);
  float bry = fminf(ay1, by1);
  float w = fmaxf(brx - tlx, 0.0f);
  float h = fmaxf(bry - tly, 0.0f);
  float inter = w * h;
  float aa = fmaxf(ax1 - ax0, 0.0f) * fmaxf(ay1 - ay0, 0.0f);
  float ab = fmaxf(bx1 - bx0, 0.0f) * fmaxf(by1 - by0, 0.0f);
  float uni = aa + ab - inter;
  return inter / fmaxf(uni, 1e-7f);
}

// dv = -(L - L1), exact expression tree of the reference cls numerator
__device__ __forceinline__ float f_dv(float p) {
  float L  = fmaxf(logf(p), -100.0f);
  float L1 = fmaxf(log1pf(-p), -100.0f);
  return -(L - L1);
}

// cost(n,g) given dv; identical op order to reference (cls = dv - sumL1).
__device__ __forceinline__ float f_cost(float iou_masked, float dv, float sumL1v,
                                        float px, float py, float sx, float sy,
                                        float bx0, float by0, float bx1, float by1,
                                        int vld) {
  if (!vld) return 100000000.0f;  // BIG
  float cls = dv - sumL1v;
  float l_ = px - bx0, t_ = py - by0, r_ = bx1 - px, b_ = by1 - py;
  bool ing = fminf(fminf(l_, t_), fminf(r_, b_)) > 0.0f;
  float gcx = (bx0 + bx1) * 0.5f;
  float gcy = (by0 + by1) * 0.5f;
  float cl = px - (gcx - 2.5f * sx);
  float ct = py - (gcy - 2.5f * sy);
  float cr = (gcx + 2.5f * sx) - px;
  float cb = (gcy + 2.5f * sy) - py;
  bool inc = fminf(fminf(cl, ct), fminf(cr, cb)) > 0.0f;
  float icost = -logf(iou_masked + 1e-7f);
  return (cls * 1.0f + icost * 3.0f) + ((ing && inc) ? 0.0f : 100000.0f);
}

// Fallback: distinct sentinel so a too-small workspace is diagnosable.
__global__ __launch_bounds__(TPB) void k_fallback(float* out, int Nout) {
  int n = blockIdx.x * blockDim.x + threadIdx.x;
  if (n >= Nout) return;
  out[n] = 0.0f;
  out[Nout + n] = -1.0f;
  out[2 * Nout + n] = -70000.0f;
}

// Kernel 1: 8 threads per anchor. valid via shfl-OR; sumL1 via 8 lane accs +
// shfl-down tree (== numpy pairwise order); optional dval table (c-major).
__global__ __launch_bounds__(TPB) void k_pre(
    const float* pred, const float* priors, const float* gtb,
    float* sumL1, u8* validArr, u32* packed, float* dval, int* mcnt,
    int N, int G, int C)
{
  __shared__ float sg[MAXG * 4];
  for (int i = threadIdx.x; i < G * 4; i += blockDim.x) sg[i] = gtb[i];
  __syncthreads();
  int t = blockIdx.x * blockDim.x + threadIdx.x;
  if (t == 0) *mcnt = 0;
  int n = t >> 3;
  int j = t & 7;
  if (n >= N) return;
  const float4 pv = reinterpret_cast<const float4*>(priors)[n];
  float px = pv.x, py = pv.y, sx = pv.z, sy = pv.w;

  int valid = 0;
  for (int g = j; g < G; g += 8) {
    float x0 = sg[g * 4 + 0], y0 = sg[g * 4 + 1], x1 = sg[g * 4 + 2], y1 = sg[g * 4 + 3];
    float l_ = px - x0, t_ = py - y0, r_ = x1 - px, b_ = y1 - py;
    bool ing = fminf(fminf(l_, t_), fminf(r_, b_)) > 0.0f;
    float gcx = (x0 + x1) * 0.5f, gcy = (y0 + y1) * 0.5f;
    float cl = px - (gcx - 2.5f * sx), ct = py - (gcy - 2.5f * sy);
    float cr = (gcx + 2.5f * sx) - px, cb = (gcy + 2.5f * sy) - py;
    bool inc = fminf(fminf(cl, ct), fminf(cr, cb)) > 0.0f;
    valid |= (ing || inc) ? 1 : 0;
  }
  valid |= __shfl_xor(valid, 1, 8);
  valid |= __shfl_xor(valid, 2, 8);
  valid |= __shfl_xor(valid, 4, 8);

  // lane j: classes i ≡ j (mod 8) ascending == numpy 8-accumulator order;
  // shfl-down tree == ((r0+r1)+(r2+r3))+((r4+r5)+(r6+r7)).
  const float* pr = pred + (size_t)n * C;
  int lim = C - (C % 8);
  float r = 0.0f;
  for (int i = j; i < lim; i += 8) {
    float p = pr[i];
    float L1 = fmaxf(log1pf(-p), -100.0f);
    r += L1;
    if (dval) {
      float L = fmaxf(logf(p), -100.0f);
      dval[(size_t)i * N + n] = -(L - L1);
    }
  }
  r += __shfl_down(r, 1, 8);
  r += __shfl_down(r, 2, 8);
  r += __shfl_down(r, 4, 8);
  if (j == 0) {
    for (int i = lim; i < C; ++i) {
      float p = pr[i];
      float L1 = fmaxf(log1pf(-p), -100.0f);
      r += L1;
      if (dval) {
        float L = fmaxf(logf(p), -100.0f);
        dval[(size_t)i * N + n] = -(L - L1);
      }
    }
    sumL1[n] = r;
    validArr[n] = (u8)valid;
    packed[n] = 0;  // ws is re-poisoned every launch — must re-zero
  }
}

// Kernel 2a: one block per (g, chunk). Per-thread stable top-10 over chunk,
// block tournament (tie -> smaller index), sorted partial lists to ws.
__global__ __launch_bounds__(TPB) void k_assign_part(
    const float* pred, const float* dval, const float* priors, const float* dec,
    const float* gtb, const int* gtl, const float* sumL1, const u8* validArr,
    float* iouV, int* iouI, float* costV, int* costI,
    int N, int G, int C)
{
  int bid = blockIdx.x;
  int g = bid / NSPLIT;
  int s = bid % NSPLIT;
  int chunk = (N + NSPLIT - 1) / NSPLIT;
  int start = s * chunk;
  int end = start + chunk; if (end > N) end = N;
  int tid = threadIdx.x;
  float bx0 = gtb[g * 4 + 0];
  float by0 = gtb[g * 4 + 1];
  float bx1 = gtb[g * 4 + 2];
  float by1 = gtb[g * 4 + 3];
  int lab = gtl[g];
  if (lab < 0) lab = 0;
  if (lab >= C) lab = C - 1;
  const float* dcol = dval ? dval + (size_t)lab * N : nullptr;

  float iv[KTOP]; int ii[KTOP];
  float cv[KTOP]; int ci[KTOP];
  for (int j = 0; j < KTOP; ++j) { iv[j] = -1e30f; ii[j] = INT_MAX; cv[j] = 1e30f; ci[j] = INT_MAX; }

  const float4* dec4 = reinterpret_cast<const float4*>(dec);
  const float4* pri4 = reinterpret_cast<const float4*>(priors);

  for (int n = start + tid; n < end; n += TPB) {
    float4 dvb = dec4[n];
    int vld = validArr[n];
    float iou = f_iou(dvb.x, dvb.y, dvb.z, dvb.w, bx0, by0, bx1, by1);
    if (!vld) iou = 0.0f;
    // stable descending insert: strict '>' keeps earlier (smaller-n) ties first
    if (iou > iv[KTOP - 1]) {
      int j = KTOP - 1;
      while (j > 0 && iou > iv[j - 1]) { iv[j] = iv[j - 1]; ii[j] = ii[j - 1]; --j; }
      iv[j] = iou; ii[j] = n;
    }
    float dv = dcol ? dcol[n] : f_dv(pred[(size_t)n * C + lab]);
    float4 pv = pri4[n];
    float c = f_cost(iou, dv, sumL1[n], pv.x, pv.y, pv.z, pv.w, bx0, by0, bx1, by1, vld);
    if (c < cv[KTOP - 1]) {
      int j = KTOP - 1;
      while (j > 0 && c < cv[j - 1]) { cv[j] = cv[j - 1]; ci[j] = ci[j - 1]; --j; }
      cv[j] = c; ci[j] = n;
    }
  }

  __shared__ float sv[TPB];
  __shared__ int   si[TPB];
  int base = bid * KTOP;

  // --- phase 1: block top-10 IoU (values+indices) ---
  for (int r = 0; r < KTOP; ++r) {
    sv[tid] = iv[0]; si[tid] = ii[0];
    __syncthreads();
    for (int st = TPB / 2; st > 0; st >>= 1) {
      if (tid < st) {
        float v2 = sv[tid + st]; int i2 = si[tid + st];
        float v1 = sv[tid];      int i1 = si[tid];
        if (v2 > v1 || (v2 == v1 && i2 < i1)) { sv[tid] = v2; si[tid] = i2; }
      }
      __syncthreads();
    }
    if (tid == 0) { iouV[base + r] = sv[0]; iouI[base + r] = si[0]; }
    int win = si[0];
    __syncthreads();   // all read si[0] before next round overwrites
    if (ii[0] == win) {  // winner pops its head (anchor indices unique)
      for (int j = 0; j < KTOP - 1; ++j) { iv[j] = iv[j + 1]; ii[j] = ii[j + 1]; }
      iv[KTOP - 1] = -1e30f; ii[KTOP - 1] = INT_MAX;
    }
  }

  // --- phase 2: block top-10 lowest cost (values+indices) ---
  for (int r = 0; r < KTOP; ++r) {
    sv[tid] = cv[0]; si[tid] = ci[0];
    __syncthreads();
    for (int st = TPB / 2; st > 0; st >>= 1) {
      if (tid < st) {
        float v2 = sv[tid + st]; int i2 = si[tid + st];
        float v1 = sv[tid];      int i1 = si[tid];
        if (v2 < v1 || (v2 == v1 && i2 < i1)) { sv[tid] = v2; si[tid] = i2; }
      }
      __syncthreads();
    }
    if (tid == 0) { costV[base + r] = sv[0]; costI[base + r] = si[0]; }
    int win = si[0];
    __syncthreads();
    if (ci[0] == win) {
      for (int j = 0; j < KTOP - 1; ++j) { cv[j] = cv[j + 1]; ci[j] = ci[j + 1]; }
      cv[KTOP - 1] = 1e30f; ci[KTOP - 1] = INT_MAX;
    }
  }
}

// Kernel 2b: one thread per g. 8-way sorted merge ((value,index) tie-break ==
// global stable top-k), dynamic_k, scatter.
__global__ __launch_bounds__(64) void k_merge(
    const float* iouV, const int* iouI, const float* costV, const int* costI,
    u32* packed, int G, int N)
{
  int g = blockIdx.x * blockDim.x + threadIdx.x;
  if (g >= G) return;
  int base = g * NSPLIT * KTOP;

  int hp[NSPLIT]; float hv[NSPLIT]; int hi[NSPLIT];
  for (int s = 0; s < NSPLIT; ++s) {
    hp[s] = 0; hv[s] = iouV[base + s * KTOP]; hi[s] = iouI[base + s * KTOP];
  }
  float rv[KTOP];
  for (int r = 0; r < KTOP; ++r) {
    int bs = 0;
    for (int s = 1; s < NSPLIT; ++s)
      if (hv[s] > hv[bs] || (hv[s] == hv[bs] && hi[s] < hi[bs])) bs = s;
    rv[r] = hv[bs];
    int p = ++hp[bs];
    if (p < KTOP) { hv[bs] = iouV[base + bs * KTOP + p]; hi[bs] = iouI[base + bs * KTOP + p]; }
    else          { hv[bs] = -1e30f; hi[bs] = INT_MAX; }
  }
  // numpy pairwise order for a 10-element sum
  float s8 = ((rv[0] + rv[1]) + (rv[2] + rv[3])) + ((rv[4] + rv[5]) + (rv[6] + rv[7]));
  s8 += rv[8];
  s8 += rv[9];
  int dk = (int)s8;  // trunc toward zero == astype(int32)
  if (dk < 1) dk = 1;
  if (dk > KTOP) dk = KTOP;

  for (int s = 0; s < NSPLIT; ++s) {
    hp[s] = 0; hv[s] = costV[base + s * KTOP]; hi[s] = costI[base + s * KTOP];
  }
  for (int r = 0; r < dk; ++r) {
    int bs = 0;
    for (int s = 1; s < NSPLIT; ++s)
      if (hv[s] < hv[bs] || (hv[s] == hv[bs] && hi[s] < hi[bs])) bs = s;
    int n = hi[bs];
    if (n >= 0 && n < N) {
      // count in high 16 bits; sum of g in low 16 (exact g when count==1)
      atomicAdd(&packed[n], (1u << 16) | (u32)g);
    }
    int p = ++hp[bs];
    if (p < KTOP) { hv[bs] = costV[base + bs * KTOP + p]; hi[bs] = costI[base + bs * KTOP + p]; }
    else          { hv[bs] = 1e30f; hi[bs] = INT_MAX; }
  }
}

// Kernel 3 stage A: resolve cnt==0/1 inline, queue cnt>1 into worklist.
__global__ __launch_bounds__(TPB) void k_final(
    const float* dec, const float* gtb, const u8* validArr, const u32* packed,
    int* mlist, int* mcnt,
    float* out, int N, int G, int Nout)
{
  __shared__ float sg[MAXG * 4];
  for (int i = threadIdx.x; i < G * 4; i += blockDim.x) sg[i] = gtb[i];
  __syncthreads();
  int n = blockIdx.x * blockDim.x + threadIdx.x;
  if (n >= N || n >= Nout) return;
  u32 pk = packed[n];
  int cnt = (int)(pk >> 16);
  float o0 = 0.0f, o1 = -1.0f, o2 = -100000.0f;
  if (cnt > 1) {
    int idx = atomicAdd(mcnt, 1);
    if (idx < MAXMULTI) mlist[idx] = n;
    // outputs for this n are written by k_multi (later kernel, no race)
  }
  if (cnt == 1) {
    int g = (int)(pk & 0xFFFFu);
    if (g < 0) g = 0;
    if (g >= G) g = G - 1;
    const float4 dv = reinterpret_cast<const float4*>(dec)[n];
    float x0 = sg[g * 4 + 0], y0 = sg[g * 4 + 1], x1 = sg[g * 4 + 2], y1 = sg[g * 4 + 3];
    float iou = f_iou(dv.x, dv.y, dv.z, dv.w, x0, y0, x1, y1);
    if (!validArr[n]) iou = 0.0f;
    o0 = (float)g; o1 = 1.0f; o2 = iou;
  }
  out[n]            = o0;
  out[Nout + n]     = o1;
  out[2 * Nout + n] = o2;
}

// Kernel 3 stage B: one 128-thread block per multi anchor (grid-stride).
// Lane gg computes cost(n,gg); LDS argmin tree, first-min tie-break == np.argmin.
#define MTPB 128
__global__ __launch_bounds__(MTPB) void k_multi(
    const float* pred, const float* dval, const float* priors, const float* dec,
    const float* gtb, const int* gtl, const float* sumL1, const u8* validArr,
    const int* mlist, const int* mcnt,
    float* out, int N, int G, int C, int Nout)
{
  __shared__ float rv[MTPB];
  __shared__ int   rg[MTPB];
  int tid = threadIdx.x;
  int total = *mcnt;
  if (total > MAXMULTI) total = MAXMULTI;
  for (int w = blockIdx.x; w < total; w += gridDim.x) {
    int n = mlist[w];
    const float4 dvb = reinterpret_cast<const float4*>(dec)[n];
    const float4 pv  = reinterpret_cast<const float4*>(priors)[n];
    float s1 = sumL1[n];
    int vld = validArr[n];
    float best = 1e30f; int bg = INT_MAX;
    for (int gg = tid; gg < G; gg += MTPB) {
      float x0 = gtb[gg * 4 + 0], y0 = gtb[gg * 4 + 1];
      float x1 = gtb[gg * 4 + 2], y1 = gtb[gg * 4 + 3];
      float iou = f_iou(dvb.x, dvb.y, dvb.z, dvb.w, x0, y0, x1, y1);
      if (!vld) iou = 0.0f;
      int lb = gtl[gg];
      if (lb < 0) lb = 0;
      if (lb >= C) lb = C - 1;
      float dv = dval ? dval[(size_t)lb * N + n] : f_dv(pred[(size_t)n * C + lb]);
      float c = f_cost(iou, dv, s1, pv.x, pv.y, pv.z, pv.w, x0, y0, x1, y1, vld);
      if (c < best || (c == best && gg < bg)) { best = c; bg = gg; }
    }
    rv[tid] = best; rg[tid] = bg;
    __syncthreads();
    for (int st = MTPB / 2; st > 0; st >>= 1) {
      if (tid < st) {
        float v2 = rv[tid + st]; int g2 = rg[tid + st];
        float v1 = rv[tid];      int g1 = rg[tid];
        if (v2 < v1 || (v2 == v1 && g2 < g1)) { rv[tid] = v2; rg[tid] = g2; }
      }
      __syncthreads();
    }
    if (tid == 0) {
      int g = rg[0];
      if (g < 0 || g >= G) g = 0;
      float x0 = gtb[g * 4 + 0], y0 = gtb[g * 4 + 1];
      float x1 = gtb[g * 4 + 2], y1 = gtb[g * 4 + 3];
      float iou = f_iou(dvb.x, dvb.y, dvb.z, dvb.w, x0, y0, x1, y1);
      if (!vld) iou = 0.0f;
      out[n]            = (float)g;
      out[Nout + n]     = 1.0f;
      out[2 * Nout + n] = iou;
    }
    __syncthreads();  // protect rv/rg before next worklist item
  }
}

extern "C" void kernel_launch(void* const* d_in, const int* in_sizes, int n_in,
                              void* d_out, int out_size, void* d_ws, size_t ws_size,
                              hipStream_t stream) {
  const float* pred   = (const float*)d_in[0];  // (N,C) f32
  const float* priors = (const float*)d_in[1];  // (N,4) f32
  const float* dec    = (const float*)d_in[2];  // (N,4) f32
  const float* gtb    = (const float*)d_in[3];  // (G,4) f32
  const int*   gtl    = (const int*)d_in[4];    // (G,)  int32
  int N = in_sizes[2] / 4;
  int G = in_sizes[3] / 4;
  if (G > MAXG) G = MAXG;
  int C = in_sizes[0] / N;
  int Nout = out_size / 3;
  float* out = (float*)d_out;

  // ws layout (all offsets 16B-aligned):
  // packed u32[N] | sumL1 f32[N] | valid u8[N] | mlist i32[MAXMULTI] | mcnt i32 |
  // lists f32/i32[4][G*NSPLIT*KTOP] | (optional) dval f32[C*N]
  size_t offPacked = 0;
  size_t offSum    = offPacked + (size_t)N * 4;
  size_t offValid  = offSum + (size_t)N * 4;
  size_t offMlist  = (offValid + (size_t)N + 15) & ~(size_t)15;
  size_t offMcnt   = offMlist + (size_t)MAXMULTI * 4;
  size_t offLists  = (offMcnt + 4 + 15) & ~(size_t)15;
  size_t plist     = (size_t)G * NSPLIT * KTOP * 4;
  size_t offDval   = offLists + plist * 4;
  size_t needSmall = offDval;
  size_t needBig   = offDval + (size_t)C * N * 4;

  dim3 b(TPB);
  int nblk = (N + TPB - 1) / TPB;
  int oblk = (Nout + TPB - 1) / TPB;
  if (ws_size < needSmall || d_ws == nullptr) {
    k_fallback<<<oblk, b, 0, stream>>>(out, Nout);  // sentinel: -70000 at out2
    return;
  }
  char* wsb = (char*)d_ws;
  u32* packed   = (u32*)(wsb + offPacked);
  float* sumL1  = (float*)(wsb + offSum);
  u8* validArr  = (u8*)(wsb + offValid);
  int* mlist    = (int*)(wsb + offMlist);
  int* mcnt     = (int*)(wsb + offMcnt);
  float* iouV   = (float*)(wsb + offLists);
  int*   iouI   = (int*)(wsb + offLists + plist);
  float* costV  = (float*)(wsb + offLists + plist * 2);
  int*   costI  = (int*)(wsb + offLists + plist * 3);
  float* dval   = (ws_size >= needBig) ? (float*)(wsb + offDval) : nullptr;

  int preblk = ((N * 8) + TPB - 1) / TPB;
  k_pre<<<preblk, b, 0, stream>>>(pred, priors, gtb, sumL1, validArr, packed, dval, mcnt, N, G, C);
  k_assign_part<<<G * NSPLIT, b, 0, stream>>>(pred, dval, priors, dec, gtb, gtl, sumL1, validArr,
                                              iouV, iouI, costV, costI, N, G, C);
  k_merge<<<(G + 63) / 64, dim3(64), 0, stream>>>(iouV, iouI, costV, costI, packed, G, N);
  k_final<<<nblk, b, 0, stream>>>(dec, gtb, validArr, packed, mlist, mcnt, out, N, G, Nout);
  k_multi<<<256, dim3(MTPB), 0, stream>>>(pred, dval, priors, dec, gtb, gtl, sumL1, validArr,
                                          mlist, mcnt, out, N, G, C, Nout);
}

// Round 7
// 165.287 us; speedup vs baseline: 2.9445x; 1.1260x over previous
//
#include <hip/hip_runtime.h>
#include <math.h>
#include <limits.h>

// Match numpy op-for-op: no fma contraction anywhere.
#pragma clang fp contract(off)

#define TPB 256
#define ATPB 64
#define KTOP 10
#define NSPLIT 32
#define MAXG 512
#define MAXMULTI 4096

typedef unsigned int u32;
typedef unsigned char u8;

// pairwise IoU, identical op order to the numpy reference
__device__ __forceinline__ float f_iou(float ax0, float ay0, float ax1, float ay1,
                                       float bx0, float by0, float bx1, float by1) {
  float tlx = fmaxf(ax0, bx0);
  float tly = fmaxf(ay0, by0);
  float brx = fminf(ax1, bx1);
  float bry = fminf(ay1, by1);
  float w = fmaxf(brx - tlx, 0.0f);
  float h = fmaxf(bry - tly, 0.0f);
  float inter = w * h;
  float aa = fmaxf(ax1 - ax0, 0.0f) * fmaxf(ay1 - ay0, 0.0f);
  float ab = fmaxf(bx1 - bx0, 0.0f) * fmaxf(by1 - by0, 0.0f);
  float uni = aa + ab - inter;
  return inter / fmaxf(uni, 1e-7f);
}

// dv = -(L - L1), exact expression tree of the reference cls numerator
__device__ __forceinline__ float f_dv(float p) {
  float L  = fmaxf(logf(p), -100.0f);
  float L1 = fmaxf(log1pf(-p), -100.0f);
  return -(L - L1);
}

// cost(n,g) given dv; identical op order to reference (cls = dv - sumL1).
__device__ __forceinline__ float f_cost(float iou_masked, float dv, float sumL1v,
                                        float px, float py, float sx, float sy,
                                        float bx0, float by0, float bx1, float by1,
                                        int vld) {
  if (!vld) return 100000000.0f;  // BIG
  float cls = dv - sumL1v;
  float l_ = px - bx0, t_ = py - by0, r_ = bx1 - px, b_ = by1 - py;
  bool ing = fminf(fminf(l_, t_), fminf(r_, b_)) > 0.0f;
  float gcx = (bx0 + bx1) * 0.5f;
  float gcy = (by0 + by1) * 0.5f;
  float cl = px - (gcx - 2.5f * sx);
  float ct = py - (gcy - 2.5f * sy);
  float cr = (gcx + 2.5f * sx) - px;
  float cb = (gcy + 2.5f * sy) - py;
  bool inc = fminf(fminf(cl, ct), fminf(cr, cb)) > 0.0f;
  float icost = -logf(iou_masked + 1e-7f);
  return (cls * 1.0f + icost * 3.0f) + ((ing && inc) ? 0.0f : 100000.0f);
}

// Fallback: distinct sentinel so a too-small workspace is diagnosable.
__global__ __launch_bounds__(TPB) void k_fallback(float* out, int Nout) {
  int n = blockIdx.x * blockDim.x + threadIdx.x;
  if (n >= Nout) return;
  out[n] = 0.0f;
  out[Nout + n] = -1.0f;
  out[2 * Nout + n] = -70000.0f;
}

// Kernel 1: 8 threads per anchor. valid via shfl-OR; sumL1 via 8 lane accs +
// shfl-down tree (== numpy pairwise order); dval table (class-major).
__global__ __launch_bounds__(TPB) void k_pre(
    const float* pred, const float* priors, const float* gtb,
    float* sumL1, u8* validArr, u32* packed, float* dval, int* mcnt,
    int N, int G, int C)
{
  __shared__ float sg[MAXG * 4];
  for (int i = threadIdx.x; i < G * 4; i += blockDim.x) sg[i] = gtb[i];
  __syncthreads();
  int t = blockIdx.x * blockDim.x + threadIdx.x;
  if (t == 0) *mcnt = 0;
  int n = t >> 3;
  int j = t & 7;
  if (n >= N) return;
  const float4 pv = reinterpret_cast<const float4*>(priors)[n];
  float px = pv.x, py = pv.y, sx = pv.z, sy = pv.w;

  int valid = 0;
  for (int g = j; g < G; g += 8) {
    float x0 = sg[g * 4 + 0], y0 = sg[g * 4 + 1], x1 = sg[g * 4 + 2], y1 = sg[g * 4 + 3];
    float l_ = px - x0, t_ = py - y0, r_ = x1 - px, b_ = y1 - py;
    bool ing = fminf(fminf(l_, t_), fminf(r_, b_)) > 0.0f;
    float gcx = (x0 + x1) * 0.5f, gcy = (y0 + y1) * 0.5f;
    float cl = px - (gcx - 2.5f * sx), ct = py - (gcy - 2.5f * sy);
    float cr = (gcx + 2.5f * sx) - px, cb = (gcy + 2.5f * sy) - py;
    bool inc = fminf(fminf(cl, ct), fminf(cr, cb)) > 0.0f;
    valid |= (ing || inc) ? 1 : 0;
  }
  valid |= __shfl_xor(valid, 1, 8);
  valid |= __shfl_xor(valid, 2, 8);
  valid |= __shfl_xor(valid, 4, 8);

  // lane j: classes i ≡ j (mod 8) ascending == numpy 8-accumulator order;
  // shfl-down tree == ((r0+r1)+(r2+r3))+((r4+r5)+(r6+r7)).
  const float* pr = pred + (size_t)n * C;
  int lim = C - (C % 8);
  float r = 0.0f;
  for (int i = j; i < lim; i += 8) {
    float p = pr[i];
    float L1 = fmaxf(log1pf(-p), -100.0f);
    r += L1;
    if (dval) {
      float L = fmaxf(logf(p), -100.0f);
      dval[(size_t)i * N + n] = -(L - L1);
    }
  }
  r += __shfl_down(r, 1, 8);
  r += __shfl_down(r, 2, 8);
  r += __shfl_down(r, 4, 8);
  if (j == 0) {
    for (int i = lim; i < C; ++i) {
      float p = pr[i];
      float L1 = fmaxf(log1pf(-p), -100.0f);
      r += L1;
      if (dval) {
        float L = fmaxf(logf(p), -100.0f);
        dval[(size_t)i * N + n] = -(L - L1);
      }
    }
    sumL1[n] = r;
    validArr[n] = (u8)valid;
    packed[n] = 0;  // ws is re-poisoned every launch — must re-zero
  }
}

// Kernel 2a: ONE WAVE per (g, split). Register-resident top-10 lists (all
// indices static via full unroll), shuffle-only tournament — no LDS, no
// __syncthreads. IoU list is values-only (sum of top-10 is tie-invariant).
__global__ __launch_bounds__(ATPB) void k_assign_part(
    const float* pred, const float* dval, const float* priors, const float* dec,
    const float* gtb, const int* gtl, const float* sumL1, const u8* validArr,
    float* iouV, float* costV, int* costI,
    int N, int G, int C)
{
  int bid = blockIdx.x;
  int g = bid / NSPLIT;
  int s = bid % NSPLIT;
  int chunk = (N + NSPLIT - 1) / NSPLIT;
  int start = s * chunk;
  int end = start + chunk; if (end > N) end = N;
  int tid = threadIdx.x;
  float bx0 = gtb[g * 4 + 0];
  float by0 = gtb[g * 4 + 1];
  float bx1 = gtb[g * 4 + 2];
  float by1 = gtb[g * 4 + 3];
  int lab = gtl[g];
  if (lab < 0) lab = 0;
  if (lab >= C) lab = C - 1;
  const float* dcol = dval ? dval + (size_t)lab * N : nullptr;

  float iv[KTOP];
  float cv[KTOP]; int ci[KTOP];
#pragma unroll
  for (int j = 0; j < KTOP; ++j) { iv[j] = -1e30f; cv[j] = 1e30f; ci[j] = INT_MAX; }

  const float4* dec4 = reinterpret_cast<const float4*>(dec);
  const float4* pri4 = reinterpret_cast<const float4*>(priors);

  for (int n = start + tid; n < end; n += ATPB) {
    float4 dvb = dec4[n];
    int vld = validArr[n];
    float iou = f_iou(dvb.x, dvb.y, dvb.z, dvb.w, bx0, by0, bx1, by1);
    if (!vld) iou = 0.0f;
    // strict '>' trickle: equal values keep earlier-scanned (smaller n) first
    if (iou > iv[KTOP - 1]) {
      float cu = iou;
#pragma unroll
      for (int j = 0; j < KTOP; ++j) {
        if (cu > iv[j]) { float tv = iv[j]; iv[j] = cu; cu = tv; }
      }
    }
    float dv = dcol ? dcol[n] : f_dv(pred[(size_t)n * C + lab]);
    float4 pv = pri4[n];
    float c = f_cost(iou, dv, sumL1[n], pv.x, pv.y, pv.z, pv.w, bx0, by0, bx1, by1, vld);
    if (c < cv[KTOP - 1]) {
      float cu = c; int cui = n;
#pragma unroll
      for (int j = 0; j < KTOP; ++j) {
        if (cu < cv[j]) { float tv = cv[j]; int ti = ci[j]; cv[j] = cu; ci[j] = cui; cu = tv; cui = ti; }
      }
    }
  }

  // --- wave tournament, IoU (values only; owner-lane tie-break for pop) ---
  float rv[KTOP];
#pragma unroll
  for (int r = 0; r < KTOP; ++r) {
    float v = iv[0]; int owner = tid;
#pragma unroll
    for (int off = 32; off > 0; off >>= 1) {
      float v2 = __shfl_down(v, off);
      int o2 = __shfl_down(owner, off);
      if (v2 > v || (v2 == v && o2 < owner)) { v = v2; owner = o2; }
    }
    float wv = __shfl(v, 0);
    int wo = __shfl(owner, 0);
    rv[r] = wv;
    if (tid == wo) {
#pragma unroll
      for (int j = 0; j < KTOP - 1; ++j) iv[j] = iv[j + 1];
      iv[KTOP - 1] = -1e30f;
    }
  }

  // --- wave tournament, cost ((value,index) lexicographic == stable) ---
  float rcv[KTOP]; int ri[KTOP];
#pragma unroll
  for (int r = 0; r < KTOP; ++r) {
    float v = cv[0]; int idx = ci[0];
#pragma unroll
    for (int off = 32; off > 0; off >>= 1) {
      float v2 = __shfl_down(v, off);
      int i2 = __shfl_down(idx, off);
      if (v2 < v || (v2 == v && i2 < idx)) { v = v2; idx = i2; }
    }
    float wv = __shfl(v, 0);
    int wi = __shfl(idx, 0);
    rcv[r] = wv; ri[r] = wi;
    if (ci[0] == wi) {  // anchor indices unique -> exactly one lane pops
#pragma unroll
      for (int j = 0; j < KTOP - 1; ++j) { cv[j] = cv[j + 1]; ci[j] = ci[j + 1]; }
      cv[KTOP - 1] = 1e30f; ci[KTOP - 1] = INT_MAX;
    }
  }

  if (tid == 0) {
    int base = bid * KTOP;
#pragma unroll
    for (int r = 0; r < KTOP; ++r) {
      iouV[base + r] = rv[r];
      costV[base + r] = rcv[r];
      costI[base + r] = ri[r];
    }
  }
}

// Kernel 2b: one 64-thread block per g. Wave-parallel: top-10 of 320 iou
// values via per-lane 5-slot lists + shfl tournament; cost merge via 32
// lane-owned heads (LDS lists) + shfl-min rounds with (value,index) tie.
__global__ __launch_bounds__(ATPB) void k_merge(
    const float* iouV, const float* costV, const int* costI,
    u32* packed, int G, int N)
{
  int g = blockIdx.x;
  int tid = threadIdx.x;
  int base = g * NSPLIT * KTOP;  // 320 entries per g

  // --- iou: top-10 of 320 values (ties value-equivalent, sum invariant) ---
  float il[5];
#pragma unroll
  for (int k = 0; k < 5; ++k) il[k] = -1e30f;
#pragma unroll
  for (int k = 0; k < 5; ++k) {
    float v = iouV[base + tid + k * ATPB];  // 64*5 == 320 exactly
#pragma unroll
    for (int j = 0; j < 5; ++j) {
      if (v > il[j]) { float tv = il[j]; il[j] = v; v = tv; }
    }
  }
  float rv[KTOP];
#pragma unroll
  for (int r = 0; r < KTOP; ++r) {
    float v = il[0]; int owner = tid;
#pragma unroll
    for (int off = 32; off > 0; off >>= 1) {
      float v2 = __shfl_down(v, off);
      int o2 = __shfl_down(owner, off);
      if (v2 > v || (v2 == v && o2 < owner)) { v = v2; owner = o2; }
    }
    float wv = __shfl(v, 0);
    int wo = __shfl(owner, 0);
    rv[r] = wv;
    if (tid == wo) {
#pragma unroll
      for (int j = 0; j < 4; ++j) il[j] = il[j + 1];
      il[4] = -1e30f;
    }
  }
  // numpy pairwise order for a 10-element sum (all lanes compute identically)
  float s8 = ((rv[0] + rv[1]) + (rv[2] + rv[3])) + ((rv[4] + rv[5]) + (rv[6] + rv[7]));
  s8 += rv[8];
  s8 += rv[9];
  int dk = (int)s8;  // trunc toward zero == astype(int32)
  if (dk < 1) dk = 1;
  if (dk > KTOP) dk = KTOP;

  // --- cost: stable 32-way merge of sorted lists ---
  __shared__ float cvL[NSPLIT * KTOP];
  __shared__ int   ciL[NSPLIT * KTOP];
  for (int t = tid; t < NSPLIT * KTOP; t += ATPB) {
    cvL[t] = costV[base + t];
    ciL[t] = costI[base + t];
  }
  __syncthreads();
  int hp = 0;
  float hv = 1e30f; int hi = INT_MAX;
  if (tid < NSPLIT) { hv = cvL[tid * KTOP]; hi = ciL[tid * KTOP]; }
  for (int r = 0; r < KTOP; ++r) {
    float v = hv; int idx = hi;
#pragma unroll
    for (int off = 32; off > 0; off >>= 1) {
      float v2 = __shfl_down(v, off);
      int i2 = __shfl_down(idx, off);
      if (v2 < v || (v2 == v && i2 < idx)) { v = v2; idx = i2; }
    }
    float wv = __shfl(v, 0);
    int wi = __shfl(idx, 0);
    if (r < dk && tid == 0 && wi >= 0 && wi < N) {
      // count in high 16 bits; sum of g in low 16 (exact g when count==1)
      atomicAdd(&packed[wi], (1u << 16) | (u32)g);
    }
    if (hi == wi && hi != INT_MAX) {  // unique owner advances
      ++hp;
      if (hp < KTOP) { hv = cvL[tid * KTOP + hp]; hi = ciL[tid * KTOP + hp]; }
      else           { hv = 1e30f; hi = INT_MAX; }
    }
  }
}

// Kernel 3 stage A: resolve cnt==0/1 inline, queue cnt>1 into worklist.
__global__ __launch_bounds__(TPB) void k_final(
    const float* dec, const float* gtb, const u8* validArr, const u32* packed,
    int* mlist, int* mcnt,
    float* out, int N, int G, int Nout)
{
  __shared__ float sg[MAXG * 4];
  for (int i = threadIdx.x; i < G * 4; i += blockDim.x) sg[i] = gtb[i];
  __syncthreads();
  int n = blockIdx.x * blockDim.x + threadIdx.x;
  if (n >= N || n >= Nout) return;
  u32 pk = packed[n];
  int cnt = (int)(pk >> 16);
  float o0 = 0.0f, o1 = -1.0f, o2 = -100000.0f;
  if (cnt > 1) {
    int idx = atomicAdd(mcnt, 1);
    if (idx < MAXMULTI) mlist[idx] = n;
    // outputs for this n are written by k_multi (later kernel, no race)
  }
  if (cnt == 1) {
    int g = (int)(pk & 0xFFFFu);
    if (g < 0) g = 0;
    if (g >= G) g = G - 1;
    const float4 dv = reinterpret_cast<const float4*>(dec)[n];
    float x0 = sg[g * 4 + 0], y0 = sg[g * 4 + 1], x1 = sg[g * 4 + 2], y1 = sg[g * 4 + 3];
    float iou = f_iou(dv.x, dv.y, dv.z, dv.w, x0, y0, x1, y1);
    if (!validArr[n]) iou = 0.0f;
    o0 = (float)g; o1 = 1.0f; o2 = iou;
  }
  out[n]            = o0;
  out[Nout + n]     = o1;
  out[2 * Nout + n] = o2;
}

// Kernel 3 stage B: one 128-thread block per multi anchor (grid-stride).
// Lane gg computes cost(n,gg); LDS argmin tree, first-min tie-break == np.argmin.
#define MTPB 128
__global__ __launch_bounds__(MTPB) void k_multi(
    const float* pred, const float* dval, const float* priors, const float* dec,
    const float* gtb, const int* gtl, const float* sumL1, const u8* validArr,
    const int* mlist, const int* mcnt,
    float* out, int N, int G, int C, int Nout)
{
  __shared__ float rv[MTPB];
  __shared__ int   rg[MTPB];
  int tid = threadIdx.x;
  int total = *mcnt;
  if (total > MAXMULTI) total = MAXMULTI;
  for (int w = blockIdx.x; w < total; w += gridDim.x) {
    int n = mlist[w];
    const float4 dvb = reinterpret_cast<const float4*>(dec)[n];
    const float4 pv  = reinterpret_cast<const float4*>(priors)[n];
    float s1 = sumL1[n];
    int vld = validArr[n];
    float best = 1e30f; int bg = INT_MAX;
    for (int gg = tid; gg < G; gg += MTPB) {
      float x0 = gtb[gg * 4 + 0], y0 = gtb[gg * 4 + 1];
      float x1 = gtb[gg * 4 + 2], y1 = gtb[gg * 4 + 3];
      float iou = f_iou(dvb.x, dvb.y, dvb.z, dvb.w, x0, y0, x1, y1);
      if (!vld) iou = 0.0f;
      int lb = gtl[gg];
      if (lb < 0) lb = 0;
      if (lb >= C) lb = C - 1;
      float dv = dval ? dval[(size_t)lb * N + n] : f_dv(pred[(size_t)n * C + lb]);
      float c = f_cost(iou, dv, s1, pv.x, pv.y, pv.z, pv.w, x0, y0, x1, y1, vld);
      if (c < best || (c == best && gg < bg)) { best = c; bg = gg; }
    }
    rv[tid] = best; rg[tid] = bg;
    __syncthreads();
    for (int st = MTPB / 2; st > 0; st >>= 1) {
      if (tid < st) {
        float v2 = rv[tid + st]; int g2 = rg[tid + st];
        float v1 = rv[tid];      int g1 = rg[tid];
        if (v2 < v1 || (v2 == v1 && g2 < g1)) { rv[tid] = v2; rg[tid] = g2; }
      }
      __syncthreads();
    }
    if (tid == 0) {
      int g = rg[0];
      if (g < 0 || g >= G) g = 0;
      float x0 = gtb[g * 4 + 0], y0 = gtb[g * 4 + 1];
      float x1 = gtb[g * 4 + 2], y1 = gtb[g * 4 + 3];
      float iou = f_iou(dvb.x, dvb.y, dvb.z, dvb.w, x0, y0, x1, y1);
      if (!vld) iou = 0.0f;
      out[n]            = (float)g;
      out[Nout + n]     = 1.0f;
      out[2 * Nout + n] = iou;
    }
    __syncthreads();  // protect rv/rg before next worklist item
  }
}

extern "C" void kernel_launch(void* const* d_in, const int* in_sizes, int n_in,
                              void* d_out, int out_size, void* d_ws, size_t ws_size,
                              hipStream_t stream) {
  const float* pred   = (const float*)d_in[0];  // (N,C) f32
  const float* priors = (const float*)d_in[1];  // (N,4) f32
  const float* dec    = (const float*)d_in[2];  // (N,4) f32
  const float* gtb    = (const float*)d_in[3];  // (G,4) f32
  const int*   gtl    = (const int*)d_in[4];    // (G,)  int32
  int N = in_sizes[2] / 4;
  int G = in_sizes[3] / 4;
  if (G > MAXG) G = MAXG;
  int C = in_sizes[0] / N;
  int Nout = out_size / 3;
  float* out = (float*)d_out;

  // ws layout (16B-aligned):
  // packed u32[N] | sumL1 f32[N] | valid u8[N] | mlist i32[MAXMULTI] | mcnt |
  // iouV f32[G*NSPLIT*10] | costV f32[...] | costI i32[...] | (opt) dval f32[C*N]
  size_t offPacked = 0;
  size_t offSum    = offPacked + (size_t)N * 4;
  size_t offValid  = offSum + (size_t)N * 4;
  size_t offMlist  = (offValid + (size_t)N + 15) & ~(size_t)15;
  size_t offMcnt   = offMlist + (size_t)MAXMULTI * 4;
  size_t offLists  = (offMcnt + 4 + 15) & ~(size_t)15;
  size_t plist     = (size_t)G * NSPLIT * KTOP * 4;
  size_t offDval   = offLists + plist * 3;
  size_t needSmall = offDval;
  size_t needBig   = offDval + (size_t)C * N * 4;

  dim3 b(TPB);
  int nblk = (N + TPB - 1) / TPB;
  int oblk = (Nout + TPB - 1) / TPB;
  if (ws_size < needSmall || d_ws == nullptr) {
    k_fallback<<<oblk, b, 0, stream>>>(out, Nout);  // sentinel: -70000 at out2
    return;
  }
  char* wsb = (char*)d_ws;
  u32* packed   = (u32*)(wsb + offPacked);
  float* sumL1  = (float*)(wsb + offSum);
  u8* validArr  = (u8*)(wsb + offValid);
  int* mlist    = (int*)(wsb + offMlist);
  int* mcnt     = (int*)(wsb + offMcnt);
  float* iouV   = (float*)(wsb + offLists);
  float* costV  = (float*)(wsb + offLists + plist);
  int*   costI  = (int*)(wsb + offLists + plist * 2);
  float* dval   = (ws_size >= needBig) ? (float*)(wsb + offDval) : nullptr;

  int preblk = ((N * 8) + TPB - 1) / TPB;
  k_pre<<<preblk, b, 0, stream>>>(pred, priors, gtb, sumL1, validArr, packed, dval, mcnt, N, G, C);
  k_assign_part<<<G * NSPLIT, dim3(ATPB), 0, stream>>>(pred, dval, priors, dec, gtb, gtl, sumL1, validArr,
                                                       iouV, costV, costI, N, G, C);
  k_merge<<<G, dim3(ATPB), 0, stream>>>(iouV, costV, costI, packed, G, N);
  k_final<<<nblk, b, 0, stream>>>(dec, gtb, validArr, packed, mlist, mcnt, out, N, G, Nout);
  k_multi<<<256, dim3(MTPB), 0, stream>>>(pred, dval, priors, dec, gtb, gtl, sumL1, validArr,
                                          mlist, mcnt, out, N, G, C, Nout);
}